// Round 3
// baseline (1038.483 us; speedup 1.0000x reference)
//
#include <hip/hip_runtime.h>
#include <stdint.h>

typedef _Float16 half8 __attribute__((ext_vector_type(8)));   // 8 fp16 = 16 B
typedef float    f32x4 __attribute__((ext_vector_type(4)));

#define BM 128
#define BN 128
#define BK 32
#define BLSTRIDE 40   // fallback path: B-tile row stride in halves

// ---------------------------------------------------------------------------
// Prepass kernels
// ---------------------------------------------------------------------------

// fp32 -> fp16 elementwise (values are exact fp16, conversion lossless).
__global__ __launch_bounds__(256)
void cvt_f32_f16(const float* __restrict__ in, _Float16* __restrict__ out, size_t n4)
{
    size_t i = (size_t)blockIdx.x * 256 + threadIdx.x;
    if (i >= n4) return;
    float4 v = ((const float4*)in)[i];
    _Float16 h4[4] = {(_Float16)v.x, (_Float16)v.y, (_Float16)v.z, (_Float16)v.w};
    *(uint2*)&out[i * 4] = *(uint2*)h4;
}

// fp32 [K][N] row-major  ->  fp16 [N][K] row-major (transpose + convert).
// 64x64 tiles via LDS. Row stride 72 halves = 144 B (16B-aligned, bank-shifted).
__global__ __launch_bounds__(256)
void transpose_cvt(const float* __restrict__ in, _Float16* __restrict__ out,
                   int Kdim, int Ndim)
{
    __shared__ __align__(16) _Float16 t[64][72];
    const int n0 = blockIdx.x * 64, k0 = blockIdx.y * 64;
    #pragma unroll
    for (int i = 0; i < 4; ++i) {
        const int kk = (threadIdx.x >> 4) + i * 16;
        const int nn = (threadIdx.x & 15) * 4;
        const float4 v = *(const float4*)&in[(size_t)(k0 + kk) * Ndim + n0 + nn];
        t[nn + 0][kk] = (_Float16)v.x;
        t[nn + 1][kk] = (_Float16)v.y;
        t[nn + 2][kk] = (_Float16)v.z;
        t[nn + 3][kk] = (_Float16)v.w;
    }
    __syncthreads();
    #pragma unroll
    for (int i = 0; i < 2; ++i) {
        const int c  = threadIdx.x + i * 256;
        const int nn = c >> 3, ck = (c & 7) * 8;
        *(half8*)&out[(size_t)(n0 + nn) * Kdim + k0 + ck] = *(const half8*)&t[nn][ck];
    }
}

// ---------------------------------------------------------------------------
// 256x256 8-phase GEMM (T1+T2+T3+T4+T5 stack). A [M][K] fp16, Bt [N][K] fp16.
// BK=64, 8 waves (2Mx4N), per-wave 128x64 output, mfma_f32_16x16x32_f16.
// LDS 128 KiB: 2 double-buffered K-tiles x (A 256x64 + B 256x64) fp16.
// Swizzle (both-sides): global source col pre-XORed, linear LDS dest,
// ds_read addr XORed with (row&7).
// Phase read balance 8/4/8/4: B-nh0 for tile t+1 is pre-read at p4 of tile t
// (guaranteed landed: p4's vmcnt(4) leaves only B(t+2) in flight) into the
// alternate fragment buffer (bX/bY, loop unrolled x2 -> static indexing).
// Epilogue: PLAIN cached stores. (r2 lesson: nontemporal dword stores bypass
// L2 write-combining -> 64B partial-line HBM writes -> RMW: WRITE +54%,
// FETCH +115 MB, +230 us. L2 is what assembles these 4B/lane stores into
// full lines; do not bypass it.)
// ---------------------------------------------------------------------------
template<int MH, int NH>
__device__ __forceinline__ void mfma_quad(const half8 (&af)[4][2], const half8 (&bf)[2][2],
                                          f32x4 (&acc)[8][4])
{
    #pragma unroll
    for (int mi = 0; mi < 4; ++mi)
        #pragma unroll
        for (int ni = 0; ni < 2; ++ni)
            #pragma unroll
            for (int ks = 0; ks < 2; ++ks)
                acc[MH * 4 + mi][NH * 2 + ni] = __builtin_amdgcn_mfma_f32_16x16x32_f16(
                    af[mi][ks], bf[ni][ks], acc[MH * 4 + mi][NH * 2 + ni], 0, 0, 0);
}

template<int KK, int NN>
__global__ __launch_bounds__(512, 2)
void gemm_tt8(const _Float16* __restrict__ A, const _Float16* __restrict__ Bt,
              float* __restrict__ C)
{
    __shared__ __align__(16) _Float16 lds[2][2][256][64];   // [buf][A=0/B=1][row][k]

    const int tid  = threadIdx.x;
    const int lane = tid & 63;
    const int w    = tid >> 6;
    const int wr   = w >> 2;           // 0..1  (m)
    const int wc   = w & 3;            // 0..3  (n)
    const int lm   = lane & 15;
    const int lk   = lane >> 4;

    // XCD swizzle: bid&7 = XCD id; one A m-panel (2 MB, L2-resident) per XCD,
    // B streamed; all XCDs walk the same bn window concurrently (L3 share).
    const int bm0 = (blockIdx.x & 7) * 256;
    const int bn0 = (int)(blockIdx.x >> 3) * 256;

    constexpr int NT = KK / 64;

    // Stage one half-tile (128 rows x 64 halves = 16 KB): 2 x 16B per thread.
    auto stage = [&](int buf, int ab, int h, int kt, const _Float16* P, int p0) {
        const int k0 = kt * 64;
        #pragma unroll
        for (int issue = 0; issue < 2; ++issue) {
            const int c  = tid + issue * 512;
            const int r  = c >> 3;                       // 0..127
            const int sc = ((c & 7) ^ (r & 7)) * 8;      // swizzled source col (halves)
            __builtin_amdgcn_global_load_lds(
                (const __attribute__((address_space(1))) uint32_t*)
                    (P + (size_t)(p0 + h * 128 + r) * KK + k0 + sc),
                (__attribute__((address_space(3))) uint32_t*)
                    &lds[buf][ab][h * 128 + r][(c & 7) * 8],
                16, 0, 0);
        }
    };

    half8 af[4][2], b1[2][2], bX[2][2], bY[2][2];
    f32x4 acc[8][4];
    #pragma unroll
    for (int i = 0; i < 8; ++i)
        #pragma unroll
        for (int j = 0; j < 4; ++j)
            acc[i][j] = (f32x4)0.0f;

    auto rdA = [&](int buf, int mh) {
        #pragma unroll
        for (int mi = 0; mi < 4; ++mi)
            #pragma unroll
            for (int ks = 0; ks < 2; ++ks) {
                const int row = wr * 128 + (mh * 4 + mi) * 16 + lm;
                af[mi][ks] = *(const half8*)
                    &lds[buf][0][row][(ks * 32 + lk * 8) ^ ((row & 7) * 8)];
            }
    };
    auto rdB = [&](int buf, int nh, half8 (&bf)[2][2]) {
        #pragma unroll
        for (int ni = 0; ni < 2; ++ni)
            #pragma unroll
            for (int ks = 0; ks < 2; ++ks) {
                const int row = wc * 64 + (nh * 2 + ni) * 16 + lm;
                bf[ni][ks] = *(const half8*)
                    &lds[buf][1][row][(ks * 32 + lk * 8) ^ ((row & 7) * 8)];
            }
    };

    // One K-tile = 4 phases. bcur = B-nh0 of this tile (pre-read); bnxt gets
    // B-nh0 of tile t+1 at p4 (after vmcnt(4) proves it landed).
    auto tile_body = [&](int t, int buf, half8 (&bcur)[2][2], half8 (&bnxt)[2][2]) {
        // ---- p1: Q(m0,n0). 8 ds_reads (A-mh0); stage A(t+1) h0
        rdA(buf, 0);
        if (t + 1 < NT) stage(buf ^ 1, 0, 0, t + 1, A, bm0);
        asm volatile("" ::: "memory");
        __builtin_amdgcn_s_barrier();
        __builtin_amdgcn_s_setprio(1);
        mfma_quad<0, 0>(af, bcur, acc);
        __builtin_amdgcn_s_setprio(0);
        asm volatile("" ::: "memory");
        __builtin_amdgcn_s_barrier();

        // ---- p2: Q(m0,n1). 4 ds_reads (B-nh1); stage A(t+1) h1
        rdB(buf, 1, b1);
        if (t + 1 < NT) stage(buf ^ 1, 0, 1, t + 1, A, bm0);
        asm volatile("" ::: "memory");
        __builtin_amdgcn_s_barrier();
        __builtin_amdgcn_s_setprio(1);
        mfma_quad<0, 1>(af, b1, acc);
        __builtin_amdgcn_s_setprio(0);
        asm volatile("" ::: "memory");
        __builtin_amdgcn_s_barrier();

        // ---- p3: Q(m1,n1). 8 ds_reads (A-mh1); stage B(t+2) h0
        rdA(buf, 1);
        if (t + 2 < NT) stage(buf, 1, 0, t + 2, Bt, bn0);
        asm volatile("" ::: "memory");
        __builtin_amdgcn_s_barrier();
        __builtin_amdgcn_s_setprio(1);
        mfma_quad<1, 1>(af, b1, acc);
        __builtin_amdgcn_s_setprio(0);
        asm volatile("" ::: "memory");
        __builtin_amdgcn_s_barrier();

        // ---- p4: Q(m1,n0). stage B(t+2) h1; counted vmcnt(4) leaves only
        // B(t+2) in flight (A(t+1) + B(t+1) + older all landed). After the
        // MFMA cluster, pre-read B(t+1)-nh0 from the other buffer (landed).
        if (t + 2 < NT) {
            stage(buf, 1, 1, t + 2, Bt, bn0);
            asm volatile("s_waitcnt vmcnt(4)" ::: "memory");
        } else {
            asm volatile("s_waitcnt vmcnt(0)" ::: "memory");
        }
        __builtin_amdgcn_s_barrier();
        __builtin_amdgcn_s_setprio(1);
        mfma_quad<1, 0>(af, bcur, acc);
        __builtin_amdgcn_s_setprio(0);
        if (t + 1 < NT) rdB(buf ^ 1, 0, bnxt);
        asm volatile("" ::: "memory");
        __builtin_amdgcn_s_barrier();
    };

    // ---- prologue: tile0 fully + tile1 B; drain to tile1's B (4 loads);
    // then pre-read B(0)-nh0.
    stage(0, 1, 0, 0, Bt, bn0);
    stage(0, 1, 1, 0, Bt, bn0);
    stage(0, 0, 0, 0, A,  bm0);
    stage(0, 0, 1, 0, A,  bm0);
    stage(1, 1, 0, 1, Bt, bn0);
    stage(1, 1, 1, 1, Bt, bn0);
    asm volatile("s_waitcnt vmcnt(4)" ::: "memory");
    __builtin_amdgcn_s_barrier();
    rdB(0, 0, bX);

    static_assert(NT % 2 == 0, "unroll-by-2 requires even tile count");
    for (int t = 0; t < NT; t += 2) {
        tile_body(t,     0, bX, bY);
        tile_body(t + 1, 1, bY, bX);
    }

    // ---- epilogue: C/D layout col=lane&15, row=(lane>>4)*4+reg. Plain stores.
    #pragma unroll
    for (int mi = 0; mi < 8; ++mi) {
        #pragma unroll
        for (int ni = 0; ni < 4; ++ni) {
            #pragma unroll
            for (int r = 0; r < 4; ++r) {
                const int orow = bm0 + wr * 128 + mi * 16 + lk * 4 + r;
                const int ocol = bn0 + wc * 64 + ni * 16 + lm;
                C[(size_t)orow * NN + ocol] = (float)(_Float16)acc[mi][ni][r];
            }
        }
    }
}

// ---------------------------------------------------------------------------
// 128x128 m97-structure GEMM (gemm1: M=2048,N=4096 -> 512 blocks at 128^2).
// ---------------------------------------------------------------------------
template<int K, int N, bool OUT_IS_F32>
__global__ __launch_bounds__(256)
void gemm_tt(const _Float16* __restrict__ A, const _Float16* __restrict__ Bt,
             void* __restrict__ Cv)
{
    __shared__ __align__(16) _Float16 As[BM * BK];   // 8 KB [m][k]
    __shared__ __align__(16) _Float16 Bs[BN * BK];   // 8 KB [n][k]

    const int tid  = threadIdx.x;
    const int lane = tid & 63;
    const int wave = tid >> 6;

    const int bm0 = blockIdx.x * BM;
    const int bn0 = blockIdx.y * BN;

    const int m_off = (wave >> 1) * 64;
    const int n_off = (wave & 1) * 64;

    const int lm = lane & 15;
    const int lk = lane >> 4;

    f32x4 acc[4][4];
    #pragma unroll
    for (int i = 0; i < 4; ++i)
        #pragma unroll
        for (int j = 0; j < 4; ++j)
            acc[i][j] = (f32x4)0.0f;

    for (int kt = 0; kt < K / BK; ++kt) {
        const int k0 = kt * BK;

        #pragma unroll
        for (int issue = 0; issue < 2; ++issue) {
            const int c = issue * 256 + tid;
            const int r = c >> 2;
            const int cc = (c & 3) * 8;
            __builtin_amdgcn_global_load_lds(
                (const __attribute__((address_space(1))) uint32_t*)
                    (A + (size_t)(bm0 + r) * K + k0 + cc),
                (__attribute__((address_space(3))) uint32_t*)&As[c * 8],
                16, 0, 0);
            __builtin_amdgcn_global_load_lds(
                (const __attribute__((address_space(1))) uint32_t*)
                    (Bt + (size_t)(bn0 + r) * K + k0 + cc),
                (__attribute__((address_space(3))) uint32_t*)&Bs[c * 8],
                16, 0, 0);
        }

        __syncthreads();

        half8 af[4], bfr[4];
        #pragma unroll
        for (int mi = 0; mi < 4; ++mi)
            af[mi] = *(const half8*)&As[(m_off + mi * 16 + lm) * BK + lk * 8];
        #pragma unroll
        for (int ni = 0; ni < 4; ++ni)
            bfr[ni] = *(const half8*)&Bs[(n_off + ni * 16 + lm) * BK + lk * 8];

        #pragma unroll
        for (int mi = 0; mi < 4; ++mi)
            #pragma unroll
            for (int ni = 0; ni < 4; ++ni)
                acc[mi][ni] = __builtin_amdgcn_mfma_f32_16x16x32_f16(
                    af[mi], bfr[ni], acc[mi][ni], 0, 0, 0);

        __syncthreads();
    }

    #pragma unroll
    for (int mi = 0; mi < 4; ++mi) {
        #pragma unroll
        for (int ni = 0; ni < 4; ++ni) {
            #pragma unroll
            for (int r = 0; r < 4; ++r) {
                const int orow = bm0 + m_off + mi * 16 + lk * 4 + r;
                const int ocol = bn0 + n_off + ni * 16 + lm;
                const _Float16 h = (_Float16)acc[mi][ni][r];
                if (OUT_IS_F32) ((float*)Cv)[(size_t)orow * N + ocol] = (float)h;
                else            ((_Float16*)Cv)[(size_t)orow * N + ocol] = h;
            }
        }
    }
}

// ---------------------------------------------------------------------------
// Fallback path (passing): NN GEMM with in-kernel transpose staging.
// ---------------------------------------------------------------------------
template<int K, int N, bool A_IS_F16, bool OUT_IS_F32>
__global__ __launch_bounds__(256)
void gemm_nn(const void* __restrict__ Av, const float* __restrict__ B,
             void* __restrict__ Cv)
{
    __shared__ __align__(16) _Float16 As[BM * BK];
    __shared__ __align__(16) _Float16 Bl[BN * BLSTRIDE];

    const int tid  = threadIdx.x;
    const int lane = tid & 63;
    const int wave = tid >> 6;
    const int bm0 = blockIdx.x * BM;
    const int bn0 = blockIdx.y * BN;
    const int m_off = (wave >> 1) * 64;
    const int n_off = (wave & 1) * 64;
    const int lm = lane & 15;
    const int lk = lane >> 4;

    f32x4 acc[4][4];
    #pragma unroll
    for (int i = 0; i < 4; ++i)
        #pragma unroll
        for (int j = 0; j < 4; ++j)
            acc[i][j] = (f32x4)0.0f;

    const int arow = tid >> 2;
    const int acol = (tid & 3) * 8;
    const int bn_local = tid & 127;
    const int kh       = tid >> 7;

    const float*    Af32 = (const float*)Av;
    const _Float16* Af16 = (const _Float16*)Av;
    const float*    Bp   = B + (size_t)(kh * 16) * N + bn0 + bn_local;

    for (int kt = 0; kt < K / BK; ++kt) {
        const int k0 = kt * BK;
        half8 a0, a1;
        if (A_IS_F16) {
            a0 = *(const half8*)(Af16 + (size_t)(bm0 + arow)      * K + k0 + acol);
            a1 = *(const half8*)(Af16 + (size_t)(bm0 + arow + 64) * K + k0 + acol);
        } else {
            const float* r0 = Af32 + (size_t)(bm0 + arow)      * K + k0 + acol;
            const float* r1 = Af32 + (size_t)(bm0 + arow + 64) * K + k0 + acol;
            float4 x0 = *(const float4*)r0, x1 = *(const float4*)(r0 + 4);
            float4 y0 = *(const float4*)r1, y1 = *(const float4*)(r1 + 4);
            a0[0]=(_Float16)x0.x; a0[1]=(_Float16)x0.y; a0[2]=(_Float16)x0.z; a0[3]=(_Float16)x0.w;
            a0[4]=(_Float16)x1.x; a0[5]=(_Float16)x1.y; a0[6]=(_Float16)x1.z; a0[7]=(_Float16)x1.w;
            a1[0]=(_Float16)y0.x; a1[1]=(_Float16)y0.y; a1[2]=(_Float16)y0.z; a1[3]=(_Float16)y0.w;
            a1[4]=(_Float16)y1.x; a1[5]=(_Float16)y1.y; a1[6]=(_Float16)y1.z; a1[7]=(_Float16)y1.w;
        }
        const float* p = Bp + (size_t)k0 * N;
        half8 w0, w1;
        #pragma unroll
        for (int i = 0; i < 8; ++i) w0[i] = (_Float16)p[(size_t)i * N];
        #pragma unroll
        for (int i = 0; i < 8; ++i) w1[i] = (_Float16)p[(size_t)(8 + i) * N];

        *(half8*)&As[arow * BK + acol]        = a0;
        *(half8*)&As[(arow + 64) * BK + acol] = a1;
        *(half8*)&Bl[bn_local * BLSTRIDE + kh * 16]     = w0;
        *(half8*)&Bl[bn_local * BLSTRIDE + kh * 16 + 8] = w1;

        __syncthreads();

        half8 af[4], bfr[4];
        #pragma unroll
        for (int mi = 0; mi < 4; ++mi)
            af[mi] = *(const half8*)&As[(m_off + mi * 16 + lm) * BK + lk * 8];
        #pragma unroll
        for (int ni = 0; ni < 4; ++ni)
            bfr[ni] = *(const half8*)&Bl[(n_off + ni * 16 + lm) * BLSTRIDE + lk * 8];

        #pragma unroll
        for (int mi = 0; mi < 4; ++mi)
            #pragma unroll
            for (int ni = 0; ni < 4; ++ni)
                acc[mi][ni] = __builtin_amdgcn_mfma_f32_16x16x32_f16(
                    af[mi], bfr[ni], acc[mi][ni], 0, 0, 0);

        __syncthreads();
    }

    #pragma unroll
    for (int mi = 0; mi < 4; ++mi) {
        #pragma unroll
        for (int ni = 0; ni < 4; ++ni) {
            #pragma unroll
            for (int r = 0; r < 4; ++r) {
                const int orow = bm0 + m_off + mi * 16 + lk * 4 + r;
                const int ocol = bn0 + n_off + ni * 16 + lm;
                const _Float16 h = (_Float16)acc[mi][ni][r];
                if (OUT_IS_F32) ((float*)Cv)[(size_t)orow * N + ocol] = (float)h;
                else            ((_Float16*)Cv)[(size_t)orow * N + ocol] = h;
            }
        }
    }
}

extern "C" void kernel_launch(void* const* d_in, const int* in_sizes, int n_in,
                              void* d_out, int out_size, void* d_ws, size_t ws_size,
                              hipStream_t stream) {
    const float* A  = (const float*)d_in[0];
    const float* Wp = (const float*)d_in[1];
    const float* Wu = (const float*)d_in[2];

    const size_t MB = 1024 * 1024;
    const size_t need = 192 * MB;   // A16(16) + Wpt(32) + Wut(128) + act(16)

    if (ws_size >= need) {
        _Float16* A16 = (_Float16*)((char*)d_ws);
        _Float16* Wpt = (_Float16*)((char*)d_ws + 16 * MB);
        _Float16* Wut = (_Float16*)((char*)d_ws + 48 * MB);
        _Float16* act = (_Float16*)((char*)d_ws + 176 * MB);

        // Prepass: convert A, transpose+convert both weights.
        cvt_f32_f16<<<(2048 * 4096 / 4 + 255) / 256, 256, 0, stream>>>(A, A16, 2048 * 4096 / 4);
        transpose_cvt<<<dim3(4096 / 64, 4096 / 64), 256, 0, stream>>>(Wp, Wpt, 4096, 4096);
        transpose_cvt<<<dim3(16384 / 64, 4096 / 64), 256, 0, stream>>>(Wu, Wut, 4096, 16384);

        // act = fp16(A @ W_prev): 128^2 m97 path (512 blocks).
        gemm_tt<4096, 4096, false>
            <<<dim3(2048 / BM, 4096 / BN), 256, 0, stream>>>(A16, Wpt, act);
        // out = fp32(fp16(act @ W_up)): 256^2 8-phase path, 8x64 = 512 blocks.
        gemm_tt8<4096, 16384>
            <<<dim3(512), 512, 0, stream>>>(act, Wut, (float*)d_out);
    } else {
        void* act = d_ws;
        gemm_nn<4096, 4096, false, false>
            <<<dim3(2048 / BM, 4096 / BN), 256, 0, stream>>>(A, Wp, act);
        gemm_nn<4096, 16384, true, true>
            <<<dim3(2048 / BM, 16384 / BN), 256, 0, stream>>>(act, Wu, d_out);
    }
}

// Round 5
// 804.766 us; speedup vs baseline: 1.2904x; 1.2904x over previous
//
#include <hip/hip_runtime.h>
#include <stdint.h>

typedef _Float16 half8 __attribute__((ext_vector_type(8)));   // 8 fp16 = 16 B
typedef float    f32x4 __attribute__((ext_vector_type(4)));

#define BM 128
#define BN 128
#define BK 32
#define BLSTRIDE 40   // fallback path: B-tile row stride in halves

// ---------------------------------------------------------------------------
// Prepass kernels
// ---------------------------------------------------------------------------

// fp32 -> fp16 elementwise (values are exact fp16, conversion lossless).
__global__ __launch_bounds__(256)
void cvt_f32_f16(const float* __restrict__ in, _Float16* __restrict__ out, size_t n4)
{
    size_t i = (size_t)blockIdx.x * 256 + threadIdx.x;
    if (i >= n4) return;
    float4 v = ((const float4*)in)[i];
    _Float16 h4[4] = {(_Float16)v.x, (_Float16)v.y, (_Float16)v.z, (_Float16)v.w};
    *(uint2*)&out[i * 4] = *(uint2*)h4;
}

// fp32 [K][N] row-major  ->  fp16 [N][K] row-major (transpose + convert).
// 64x64 tiles via LDS. Row stride 72 halves = 144 B (16B-aligned).
// TAG distinguishes Wp vs Wu instantiations in profiles.
// Diagonal block remap: decorrelates the power-of-2 (64 KB) row-pitch reads
// across HBM channels (concurrent blocks no longer share the same k0 rows).
template<int TAG>
__global__ __launch_bounds__(256)
void transpose_cvt(const float* __restrict__ in, _Float16* __restrict__ out,
                   int Kdim, int Ndim)
{
    __shared__ __align__(16) _Float16 t[64][72];
    const int bx = ((int)blockIdx.x + (int)blockIdx.y) % (int)gridDim.x;  // diagonal
    const int n0 = bx * 64, k0 = blockIdx.y * 64;
    #pragma unroll
    for (int i = 0; i < 4; ++i) {
        const int kk = (threadIdx.x >> 4) + i * 16;
        const int nn = (threadIdx.x & 15) * 4;
        const float4 v = *(const float4*)&in[(size_t)(k0 + kk) * Ndim + n0 + nn];
        t[nn + 0][kk] = (_Float16)v.x;
        t[nn + 1][kk] = (_Float16)v.y;
        t[nn + 2][kk] = (_Float16)v.z;
        t[nn + 3][kk] = (_Float16)v.w;
    }
    __syncthreads();
    #pragma unroll
    for (int i = 0; i < 2; ++i) {
        const int c  = threadIdx.x + i * 256;
        const int nn = c >> 3, ck = (c & 7) * 8;
        *(half8*)&out[(size_t)(n0 + nn) * Kdim + k0 + ck] = *(const half8*)&t[nn][ck];
    }
}

// ---------------------------------------------------------------------------
// 256x256 8-phase GEMM — r1 configuration EXACTLY (best measured: 256 us,
// MfmaUtil 49%). A [M][K] fp16, Bt [N][K] fp16.
// BK=64, 8 waves (2Mx4N), per-wave 128x64 output, mfma_f32_16x16x32_f16.
// LDS 128 KiB: 2 double-buffered K-tiles x (A 256x64 + B 256x64) fp16.
// Swizzle (both-sides): global source col pre-XORed, linear LDS dest,
// ds_read addr XORed with (row&7). Counted vmcnt(4) once per K-tile.
// r2/r3 lesson: the p4 B-pre-read rotation (8/4/8/4 balance) HALVED MfmaUtil
// (49->23) — do not reintroduce. r2 lesson: nontemporal dword stores bypass
// L2 write-combining -> partial-line HBM RMW; keep plain cached stores.
// ---------------------------------------------------------------------------
template<int MH, int NH>
__device__ __forceinline__ void mfma_quad(const half8 (&af)[4][2], const half8 (&bf)[2][2],
                                          f32x4 (&acc)[8][4])
{
    #pragma unroll
    for (int mi = 0; mi < 4; ++mi)
        #pragma unroll
        for (int ni = 0; ni < 2; ++ni)
            #pragma unroll
            for (int ks = 0; ks < 2; ++ks)
                acc[MH * 4 + mi][NH * 2 + ni] = __builtin_amdgcn_mfma_f32_16x16x32_f16(
                    af[mi][ks], bf[ni][ks], acc[MH * 4 + mi][NH * 2 + ni], 0, 0, 0);
}

template<int KK, int NN>
__global__ __launch_bounds__(512, 2)
void gemm_tt8(const _Float16* __restrict__ A, const _Float16* __restrict__ Bt,
              float* __restrict__ C)
{
    __shared__ __align__(16) _Float16 lds[2][2][256][64];   // [buf][A=0/B=1][row][k]

    const int tid  = threadIdx.x;
    const int lane = tid & 63;
    const int w    = tid >> 6;
    const int wr   = w >> 2;           // 0..1  (m)
    const int wc   = w & 3;            // 0..3  (n)
    const int lm   = lane & 15;
    const int lk   = lane >> 4;

    // XCD swizzle: bid&7 = XCD id; one A m-panel (2 MB, L2-resident) per XCD,
    // B streamed; all XCDs walk the same bn window concurrently (L3 share).
    const int bm0 = (blockIdx.x & 7) * 256;
    const int bn0 = (int)(blockIdx.x >> 3) * 256;

    constexpr int NT = KK / 64;

    // Stage one half-tile (128 rows x 64 halves = 16 KB): 2 x 16B per thread.
    auto stage = [&](int buf, int ab, int h, int kt, const _Float16* P, int p0) {
        const int k0 = kt * 64;
        #pragma unroll
        for (int issue = 0; issue < 2; ++issue) {
            const int c  = tid + issue * 512;
            const int r  = c >> 3;                       // 0..127
            const int sc = ((c & 7) ^ (r & 7)) * 8;      // swizzled source col (halves)
            __builtin_amdgcn_global_load_lds(
                (const __attribute__((address_space(1))) uint32_t*)
                    (P + (size_t)(p0 + h * 128 + r) * KK + k0 + sc),
                (__attribute__((address_space(3))) uint32_t*)
                    &lds[buf][ab][h * 128 + r][(c & 7) * 8],
                16, 0, 0);
        }
    };

    half8 af[4][2], b0[2][2], b1[2][2];
    f32x4 acc[8][4];
    #pragma unroll
    for (int i = 0; i < 8; ++i)
        #pragma unroll
        for (int j = 0; j < 4; ++j)
            acc[i][j] = (f32x4)0.0f;

    auto rdA = [&](int buf, int mh) {
        #pragma unroll
        for (int mi = 0; mi < 4; ++mi)
            #pragma unroll
            for (int ks = 0; ks < 2; ++ks) {
                const int row = wr * 128 + (mh * 4 + mi) * 16 + lm;
                af[mi][ks] = *(const half8*)
                    &lds[buf][0][row][(ks * 32 + lk * 8) ^ ((row & 7) * 8)];
            }
    };
    auto rdB = [&](int buf, int nh, half8 (&bf)[2][2]) {
        #pragma unroll
        for (int ni = 0; ni < 2; ++ni)
            #pragma unroll
            for (int ks = 0; ks < 2; ++ks) {
                const int row = wc * 64 + (nh * 2 + ni) * 16 + lm;
                bf[ni][ks] = *(const half8*)
                    &lds[buf][1][row][(ks * 32 + lk * 8) ^ ((row & 7) * 8)];
            }
    };

    // ---- prologue: tile0 fully + tile1 B-halves; drain to tile1's B (4 loads)
    stage(0, 1, 0, 0, Bt, bn0);
    stage(0, 1, 1, 0, Bt, bn0);
    stage(0, 0, 0, 0, A,  bm0);
    stage(0, 0, 1, 0, A,  bm0);
    stage(1, 1, 0, 1, Bt, bn0);
    stage(1, 1, 1, 1, Bt, bn0);
    asm volatile("s_waitcnt vmcnt(4)" ::: "memory");
    __builtin_amdgcn_s_barrier();

    for (int t = 0; t < NT; ++t) {
        const int buf = t & 1;

        // ---- phase 1: Q(m0,n0). reads A-mh0 (8xb128) + B-nh0 (4xb128) = 12
        rdA(buf, 0);
        rdB(buf, 0, b0);
        if (t + 1 < NT) stage(buf ^ 1, 0, 0, t + 1, A, bm0);
        asm volatile("" ::: "memory");
        __builtin_amdgcn_s_barrier();
        __builtin_amdgcn_s_setprio(1);
        mfma_quad<0, 0>(af, b0, acc);
        __builtin_amdgcn_s_setprio(0);
        asm volatile("" ::: "memory");
        __builtin_amdgcn_s_barrier();

        // ---- phase 2: Q(m0,n1). reads B-nh1 (4)
        rdB(buf, 1, b1);
        if (t + 1 < NT) stage(buf ^ 1, 0, 1, t + 1, A, bm0);
        asm volatile("" ::: "memory");
        __builtin_amdgcn_s_barrier();
        __builtin_amdgcn_s_setprio(1);
        mfma_quad<0, 1>(af, b1, acc);
        __builtin_amdgcn_s_setprio(0);
        asm volatile("" ::: "memory");
        __builtin_amdgcn_s_barrier();

        // ---- phase 3: Q(m1,n1). reads A-mh1 (8); B-half0 free (last read p2)
        rdA(buf, 1);
        if (t + 2 < NT) stage(buf, 1, 0, t + 2, Bt, bn0);
        asm volatile("" ::: "memory");
        __builtin_amdgcn_s_barrier();
        __builtin_amdgcn_s_setprio(1);
        mfma_quad<1, 1>(af, b1, acc);
        __builtin_amdgcn_s_setprio(0);
        asm volatile("" ::: "memory");
        __builtin_amdgcn_s_barrier();

        // ---- phase 4: Q(m1,n0). no reads (af from p3, b0 held since p1).
        // Counted drain: leave only (t+2).B0/B1 (4 loads) in flight.
        if (t + 2 < NT) {
            stage(buf, 1, 1, t + 2, Bt, bn0);
            asm volatile("s_waitcnt vmcnt(4)" ::: "memory");
        } else {
            asm volatile("s_waitcnt vmcnt(0)" ::: "memory");
        }
        __builtin_amdgcn_s_barrier();
        __builtin_amdgcn_s_setprio(1);
        mfma_quad<1, 0>(af, b0, acc);
        __builtin_amdgcn_s_setprio(0);
        asm volatile("" ::: "memory");
        __builtin_amdgcn_s_barrier();
    }

    // ---- epilogue: C/D layout col=lane&15, row=(lane>>4)*4+reg. Plain stores.
    #pragma unroll
    for (int mi = 0; mi < 8; ++mi) {
        #pragma unroll
        for (int ni = 0; ni < 4; ++ni) {
            #pragma unroll
            for (int r = 0; r < 4; ++r) {
                const int orow = bm0 + wr * 128 + mi * 16 + lk * 4 + r;
                const int ocol = bn0 + wc * 64 + ni * 16 + lm;
                C[(size_t)orow * NN + ocol] = (float)(_Float16)acc[mi][ni][r];
            }
        }
    }
}

// ---------------------------------------------------------------------------
// 128x128 m97-structure GEMM (gemm1: M=2048,N=4096 -> 512 blocks at 128^2).
// ---------------------------------------------------------------------------
template<int K, int N, bool OUT_IS_F32>
__global__ __launch_bounds__(256)
void gemm_tt(const _Float16* __restrict__ A, const _Float16* __restrict__ Bt,
             void* __restrict__ Cv)
{
    __shared__ __align__(16) _Float16 As[BM * BK];   // 8 KB [m][k]
    __shared__ __align__(16) _Float16 Bs[BN * BK];   // 8 KB [n][k]

    const int tid  = threadIdx.x;
    const int lane = tid & 63;
    const int wave = tid >> 6;

    const int bm0 = blockIdx.x * BM;
    const int bn0 = blockIdx.y * BN;

    const int m_off = (wave >> 1) * 64;
    const int n_off = (wave & 1) * 64;

    const int lm = lane & 15;
    const int lk = lane >> 4;

    f32x4 acc[4][4];
    #pragma unroll
    for (int i = 0; i < 4; ++i)
        #pragma unroll
        for (int j = 0; j < 4; ++j)
            acc[i][j] = (f32x4)0.0f;

    for (int kt = 0; kt < K / BK; ++kt) {
        const int k0 = kt * BK;

        #pragma unroll
        for (int issue = 0; issue < 2; ++issue) {
            const int c = issue * 256 + tid;
            const int r = c >> 2;
            const int cc = (c & 3) * 8;
            __builtin_amdgcn_global_load_lds(
                (const __attribute__((address_space(1))) uint32_t*)
                    (A + (size_t)(bm0 + r) * K + k0 + cc),
                (__attribute__((address_space(3))) uint32_t*)&As[c * 8],
                16, 0, 0);
            __builtin_amdgcn_global_load_lds(
                (const __attribute__((address_space(1))) uint32_t*)
                    (Bt + (size_t)(bn0 + r) * K + k0 + cc),
                (__attribute__((address_space(3))) uint32_t*)&Bs[c * 8],
                16, 0, 0);
        }

        __syncthreads();

        half8 af[4], bfr[4];
        #pragma unroll
        for (int mi = 0; mi < 4; ++mi)
            af[mi] = *(const half8*)&As[(m_off + mi * 16 + lm) * BK + lk * 8];
        #pragma unroll
        for (int ni = 0; ni < 4; ++ni)
            bfr[ni] = *(const half8*)&Bs[(n_off + ni * 16 + lm) * BK + lk * 8];

        #pragma unroll
        for (int mi = 0; mi < 4; ++mi)
            #pragma unroll
            for (int ni = 0; ni < 4; ++ni)
                acc[mi][ni] = __builtin_amdgcn_mfma_f32_16x16x32_f16(
                    af[mi], bfr[ni], acc[mi][ni], 0, 0, 0);

        __syncthreads();
    }

    #pragma unroll
    for (int mi = 0; mi < 4; ++mi) {
        #pragma unroll
        for (int ni = 0; ni < 4; ++ni) {
            #pragma unroll
            for (int r = 0; r < 4; ++r) {
                const int orow = bm0 + m_off + mi * 16 + lk * 4 + r;
                const int ocol = bn0 + n_off + ni * 16 + lm;
                const _Float16 h = (_Float16)acc[mi][ni][r];
                if (OUT_IS_F32) ((float*)Cv)[(size_t)orow * N + ocol] = (float)h;
                else            ((_Float16*)Cv)[(size_t)orow * N + ocol] = h;
            }
        }
    }
}

// ---------------------------------------------------------------------------
// Fallback path (passing): NN GEMM with in-kernel transpose staging.
// ---------------------------------------------------------------------------
template<int K, int N, bool A_IS_F16, bool OUT_IS_F32>
__global__ __launch_bounds__(256)
void gemm_nn(const void* __restrict__ Av, const float* __restrict__ B,
             void* __restrict__ Cv)
{
    __shared__ __align__(16) _Float16 As[BM * BK];
    __shared__ __align__(16) _Float16 Bl[BN * BLSTRIDE];

    const int tid  = threadIdx.x;
    const int lane = tid & 63;
    const int wave = tid >> 6;
    const int bm0 = blockIdx.x * BM;
    const int bn0 = blockIdx.y * BN;
    const int m_off = (wave >> 1) * 64;
    const int n_off = (wave & 1) * 64;
    const int lm = lane & 15;
    const int lk = lane >> 4;

    f32x4 acc[4][4];
    #pragma unroll
    for (int i = 0; i < 4; ++i)
        #pragma unroll
        for (int j = 0; j < 4; ++j)
            acc[i][j] = (f32x4)0.0f;

    const int arow = tid >> 2;
    const int acol = (tid & 3) * 8;
    const int bn_local = tid & 127;
    const int kh       = tid >> 7;

    const float*    Af32 = (const float*)Av;
    const _Float16* Af16 = (const _Float16*)Av;
    const float*    Bp   = B + (size_t)(kh * 16) * N + bn0 + bn_local;

    for (int kt = 0; kt < K / BK; ++kt) {
        const int k0 = kt * BK;
        half8 a0, a1;
        if (A_IS_F16) {
            a0 = *(const half8*)(Af16 + (size_t)(bm0 + arow)      * K + k0 + acol);
            a1 = *(const half8*)(Af16 + (size_t)(bm0 + arow + 64) * K + k0 + acol);
        } else {
            const float* r0 = Af32 + (size_t)(bm0 + arow)      * K + k0 + acol;
            const float* r1 = Af32 + (size_t)(bm0 + arow + 64) * K + k0 + acol;
            float4 x0 = *(const float4*)r0, x1 = *(const float4*)(r0 + 4);
            float4 y0 = *(const float4*)r1, y1 = *(const float4*)(r1 + 4);
            a0[0]=(_Float16)x0.x; a0[1]=(_Float16)x0.y; a0[2]=(_Float16)x0.z; a0[3]=(_Float16)x0.w;
            a0[4]=(_Float16)x1.x; a0[5]=(_Float16)x1.y; a0[6]=(_Float16)x1.z; a0[7]=(_Float16)x1.w;
            a1[0]=(_Float16)y0.x; a1[1]=(_Float16)y0.y; a1[2]=(_Float16)y0.z; a1[3]=(_Float16)y0.w;
            a1[4]=(_Float16)y1.x; a1[5]=(_Float16)y1.y; a1[6]=(_Float16)y1.z; a1[7]=(_Float16)y1.w;
        }
        const float* p = Bp + (size_t)k0 * N;
        half8 w0, w1;
        #pragma unroll
        for (int i = 0; i < 8; ++i) w0[i] = (_Float16)p[(size_t)i * N];
        #pragma unroll
        for (int i = 0; i < 8; ++i) w1[i] = (_Float16)p[(size_t)(8 + i) * N];

        *(half8*)&As[arow * BK + acol]        = a0;
        *(half8*)&As[(arow + 64) * BK + acol] = a1;
        *(half8*)&Bl[bn_local * BLSTRIDE + kh * 16]     = w0;
        *(half8*)&Bl[bn_local * BLSTRIDE + kh * 16 + 8] = w1;

        __syncthreads();

        half8 af[4], bfr[4];
        #pragma unroll
        for (int mi = 0; mi < 4; ++mi)
            af[mi] = *(const half8*)&As[(m_off + mi * 16 + lm) * BK + lk * 8];
        #pragma unroll
        for (int ni = 0; ni < 4; ++ni)
            bfr[ni] = *(const half8*)&Bl[(n_off + ni * 16 + lm) * BLSTRIDE + lk * 8];

        #pragma unroll
        for (int mi = 0; mi < 4; ++mi)
            #pragma unroll
            for (int ni = 0; ni < 4; ++ni)
                acc[mi][ni] = __builtin_amdgcn_mfma_f32_16x16x32_f16(
                    af[mi], bfr[ni], acc[mi][ni], 0, 0, 0);

        __syncthreads();
    }

    #pragma unroll
    for (int mi = 0; mi < 4; ++mi) {
        #pragma unroll
        for (int ni = 0; ni < 4; ++ni) {
            #pragma unroll
            for (int r = 0; r < 4; ++r) {
                const int orow = bm0 + m_off + mi * 16 + lk * 4 + r;
                const int ocol = bn0 + n_off + ni * 16 + lm;
                const _Float16 h = (_Float16)acc[mi][ni][r];
                if (OUT_IS_F32) ((float*)Cv)[(size_t)orow * N + ocol] = (float)h;
                else            ((_Float16*)Cv)[(size_t)orow * N + ocol] = h;
            }
        }
    }
}

extern "C" void kernel_launch(void* const* d_in, const int* in_sizes, int n_in,
                              void* d_out, int out_size, void* d_ws, size_t ws_size,
                              hipStream_t stream) {
    const float* A  = (const float*)d_in[0];
    const float* Wp = (const float*)d_in[1];
    const float* Wu = (const float*)d_in[2];

    const size_t MB = 1024 * 1024;
    const size_t need = 192 * MB;   // A16(16) + Wpt(32) + Wut(128) + act(16)

    if (ws_size >= need) {
        _Float16* A16 = (_Float16*)((char*)d_ws);
        _Float16* Wpt = (_Float16*)((char*)d_ws + 16 * MB);
        _Float16* Wut = (_Float16*)((char*)d_ws + 48 * MB);
        _Float16* act = (_Float16*)((char*)d_ws + 176 * MB);

        // Prepass: convert A, transpose+convert both weights (tagged kernels).
        cvt_f32_f16<<<(2048 * 4096 / 4 + 255) / 256, 256, 0, stream>>>(A, A16, 2048 * 4096 / 4);
        transpose_cvt<0><<<dim3(4096 / 64, 4096 / 64), 256, 0, stream>>>(Wp, Wpt, 4096, 4096);
        transpose_cvt<1><<<dim3(16384 / 64, 4096 / 64), 256, 0, stream>>>(Wu, Wut, 4096, 16384);

        // act = fp16(A @ W_prev): 128^2 m97 path (512 blocks).
        gemm_tt<4096, 4096, false>
            <<<dim3(2048 / BM, 4096 / BN), 256, 0, stream>>>(A16, Wpt, act);
        // out = fp32(fp16(act @ W_up)): 256^2 8-phase path (r1 config).
        gemm_tt8<4096, 16384>
            <<<dim3(512), 512, 0, stream>>>(act, Wut, (float*)d_out);
    } else {
        void* act = d_ws;
        gemm_nn<4096, 4096, false, false>
            <<<dim3(2048 / BM, 4096 / BN), 256, 0, stream>>>(A, Wp, act);
        gemm_nn<4096, 16384, true, true>
            <<<dim3(2048 / BM, 16384 / BN), 256, 0, stream>>>(act, Wu, d_out);
    }
}

// Round 6
// 800.844 us; speedup vs baseline: 1.2967x; 1.0049x over previous
//
#include <hip/hip_runtime.h>
#include <stdint.h>

typedef _Float16 half8 __attribute__((ext_vector_type(8)));   // 8 fp16 = 16 B
typedef float    f32x4 __attribute__((ext_vector_type(4)));

#define BM 128
#define BN 128
#define BK 32
#define BLSTRIDE 40   // fallback path: B-tile row stride in halves

// ---------------------------------------------------------------------------
// Prepass kernels
// ---------------------------------------------------------------------------

// fp32 -> fp16 elementwise (values are exact fp16, conversion lossless).
__global__ __launch_bounds__(256)
void cvt_f32_f16(const float* __restrict__ in, _Float16* __restrict__ out, size_t n4)
{
    size_t i = (size_t)blockIdx.x * 256 + threadIdx.x;
    if (i >= n4) return;
    float4 v = ((const float4*)in)[i];
    _Float16 h4[4] = {(_Float16)v.x, (_Float16)v.y, (_Float16)v.z, (_Float16)v.w};
    *(uint2*)&out[i * 4] = *(uint2*)h4;
}

// fp32 [K][N] row-major  ->  fp16 [N][K] row-major (transpose + convert).
// 64x64 tiles via LDS. Row stride 72 halves = 144 B (16B-aligned).
// Diagonal remap measured NEUTRAL (r5) — kept, harmless.
template<int TAG>
__global__ __launch_bounds__(256)
void transpose_cvt(const float* __restrict__ in, _Float16* __restrict__ out,
                   int Kdim, int Ndim)
{
    __shared__ __align__(16) _Float16 t[64][72];
    const int bx = ((int)blockIdx.x + (int)blockIdx.y) % (int)gridDim.x;  // diagonal
    const int n0 = bx * 64, k0 = blockIdx.y * 64;
    #pragma unroll
    for (int i = 0; i < 4; ++i) {
        const int kk = (threadIdx.x >> 4) + i * 16;
        const int nn = (threadIdx.x & 15) * 4;
        const float4 v = *(const float4*)&in[(size_t)(k0 + kk) * Ndim + n0 + nn];
        t[nn + 0][kk] = (_Float16)v.x;
        t[nn + 1][kk] = (_Float16)v.y;
        t[nn + 2][kk] = (_Float16)v.z;
        t[nn + 3][kk] = (_Float16)v.w;
    }
    __syncthreads();
    #pragma unroll
    for (int i = 0; i < 2; ++i) {
        const int c  = threadIdx.x + i * 256;
        const int nn = c >> 3, ck = (c & 7) * 8;
        *(half8*)&out[(size_t)(n0 + nn) * Kdim + k0 + ck] = *(const half8*)&t[nn][ck];
    }
}

// ---------------------------------------------------------------------------
// 256x256 8-phase GEMM. A [M][K] fp16, Bt [N][K] fp16. r1 schedule EXACTLY
// (measured: ~251 us, MfmaUtil 49%, conflicts 0). ONLY change this round:
// block->tile mapping pins B panels per XCD instead of A panels.
//   r5 evidence: A-pinned mapping streamed ALL 64 bn panels (128 MB) through
//   every XCD's L2 -> FETCH 540 MB (~4x B over-fetch); L3 cross-XCD sharing
//   decays with drift + 128 MB C-write churn. B-pinned: each bn panel is
//   owned by exactly one XCD and hot for 8 consecutive bm-blocks -> B fetched
//   ~once (128 MB); A (16 MB) is L3-resident by construction.
// r2/r3 lesson: do NOT touch the phase schedule (p4 B-pre-read rotation
// halved MfmaUtil). r2 lesson: no nontemporal dword stores (L2 assembles
// partial lines; bypassing it causes HBM RMW).
// ---------------------------------------------------------------------------
template<int MH, int NH>
__device__ __forceinline__ void mfma_quad(const half8 (&af)[4][2], const half8 (&bf)[2][2],
                                          f32x4 (&acc)[8][4])
{
    #pragma unroll
    for (int mi = 0; mi < 4; ++mi)
        #pragma unroll
        for (int ni = 0; ni < 2; ++ni)
            #pragma unroll
            for (int ks = 0; ks < 2; ++ks)
                acc[MH * 4 + mi][NH * 2 + ni] = __builtin_amdgcn_mfma_f32_16x16x32_f16(
                    af[mi][ks], bf[ni][ks], acc[MH * 4 + mi][NH * 2 + ni], 0, 0, 0);
}

template<int KK, int NN>
__global__ __launch_bounds__(512, 2)
void gemm_tt8(const _Float16* __restrict__ A, const _Float16* __restrict__ Bt,
              float* __restrict__ C)
{
    __shared__ __align__(16) _Float16 lds[2][2][256][64];   // [buf][A=0/B=1][row][k]

    const int tid  = threadIdx.x;
    const int lane = tid & 63;
    const int w    = tid >> 6;
    const int wr   = w >> 2;           // 0..1  (m)
    const int wc   = w & 3;            // 0..3  (n)
    const int lm   = lane & 15;
    const int lk   = lane >> 4;

    // B-pinned XCD mapping (bijective over 8 xcd x 8 group x 8 bm = 512):
    //   xcd owns bn panels [xcd*8, xcd*8+8); within a group the 8 bm-blocks
    //   are temporally adjacent -> one B panel fetch serves all 8.
    const int xcd = (int)blockIdx.x & 7;
    const int i   = (int)blockIdx.x >> 3;
    const int bn0 = (xcd * 8 + (i >> 3)) * 256;
    const int bm0 = (i & 7) * 256;

    constexpr int NT = KK / 64;

    // Stage one half-tile (128 rows x 64 halves = 16 KB): 2 x 16B per thread.
    auto stage = [&](int buf, int ab, int h, int kt, const _Float16* P, int p0) {
        const int k0 = kt * 64;
        #pragma unroll
        for (int issue = 0; issue < 2; ++issue) {
            const int c  = tid + issue * 512;
            const int r  = c >> 3;                       // 0..127
            const int sc = ((c & 7) ^ (r & 7)) * 8;      // swizzled source col (halves)
            __builtin_amdgcn_global_load_lds(
                (const __attribute__((address_space(1))) uint32_t*)
                    (P + (size_t)(p0 + h * 128 + r) * KK + k0 + sc),
                (__attribute__((address_space(3))) uint32_t*)
                    &lds[buf][ab][h * 128 + r][(c & 7) * 8],
                16, 0, 0);
        }
    };

    half8 af[4][2], b0[2][2], b1[2][2];
    f32x4 acc[8][4];
    #pragma unroll
    for (int i2 = 0; i2 < 8; ++i2)
        #pragma unroll
        for (int j = 0; j < 4; ++j)
            acc[i2][j] = (f32x4)0.0f;

    auto rdA = [&](int buf, int mh) {
        #pragma unroll
        for (int mi = 0; mi < 4; ++mi)
            #pragma unroll
            for (int ks = 0; ks < 2; ++ks) {
                const int row = wr * 128 + (mh * 4 + mi) * 16 + lm;
                af[mi][ks] = *(const half8*)
                    &lds[buf][0][row][(ks * 32 + lk * 8) ^ ((row & 7) * 8)];
            }
    };
    auto rdB = [&](int buf, int nh, half8 (&bf)[2][2]) {
        #pragma unroll
        for (int ni = 0; ni < 2; ++ni)
            #pragma unroll
            for (int ks = 0; ks < 2; ++ks) {
                const int row = wc * 64 + (nh * 2 + ni) * 16 + lm;
                bf[ni][ks] = *(const half8*)
                    &lds[buf][1][row][(ks * 32 + lk * 8) ^ ((row & 7) * 8)];
            }
    };

    // ---- prologue: tile0 fully + tile1 B-halves; drain to tile1's B (4 loads)
    stage(0, 1, 0, 0, Bt, bn0);
    stage(0, 1, 1, 0, Bt, bn0);
    stage(0, 0, 0, 0, A,  bm0);
    stage(0, 0, 1, 0, A,  bm0);
    stage(1, 1, 0, 1, Bt, bn0);
    stage(1, 1, 1, 1, Bt, bn0);
    asm volatile("s_waitcnt vmcnt(4)" ::: "memory");
    __builtin_amdgcn_s_barrier();

    for (int t = 0; t < NT; ++t) {
        const int buf = t & 1;

        // ---- phase 1: Q(m0,n0). reads A-mh0 (8xb128) + B-nh0 (4xb128) = 12
        rdA(buf, 0);
        rdB(buf, 0, b0);
        if (t + 1 < NT) stage(buf ^ 1, 0, 0, t + 1, A, bm0);
        asm volatile("" ::: "memory");
        __builtin_amdgcn_s_barrier();
        __builtin_amdgcn_s_setprio(1);
        mfma_quad<0, 0>(af, b0, acc);
        __builtin_amdgcn_s_setprio(0);
        asm volatile("" ::: "memory");
        __builtin_amdgcn_s_barrier();

        // ---- phase 2: Q(m0,n1). reads B-nh1 (4)
        rdB(buf, 1, b1);
        if (t + 1 < NT) stage(buf ^ 1, 0, 1, t + 1, A, bm0);
        asm volatile("" ::: "memory");
        __builtin_amdgcn_s_barrier();
        __builtin_amdgcn_s_setprio(1);
        mfma_quad<0, 1>(af, b1, acc);
        __builtin_amdgcn_s_setprio(0);
        asm volatile("" ::: "memory");
        __builtin_amdgcn_s_barrier();

        // ---- phase 3: Q(m1,n1). reads A-mh1 (8); B-half0 free (last read p2)
        rdA(buf, 1);
        if (t + 2 < NT) stage(buf, 1, 0, t + 2, Bt, bn0);
        asm volatile("" ::: "memory");
        __builtin_amdgcn_s_barrier();
        __builtin_amdgcn_s_setprio(1);
        mfma_quad<1, 1>(af, b1, acc);
        __builtin_amdgcn_s_setprio(0);
        asm volatile("" ::: "memory");
        __builtin_amdgcn_s_barrier();

        // ---- phase 4: Q(m1,n0). no reads (af from p3, b0 held since p1).
        // Counted drain: leave only (t+2).B0/B1 (4 loads) in flight.
        if (t + 2 < NT) {
            stage(buf, 1, 1, t + 2, Bt, bn0);
            asm volatile("s_waitcnt vmcnt(4)" ::: "memory");
        } else {
            asm volatile("s_waitcnt vmcnt(0)" ::: "memory");
        }
        __builtin_amdgcn_s_barrier();
        __builtin_amdgcn_s_setprio(1);
        mfma_quad<1, 0>(af, b0, acc);
        __builtin_amdgcn_s_setprio(0);
        asm volatile("" ::: "memory");
        __builtin_amdgcn_s_barrier();
    }

    // ---- epilogue: C/D layout col=lane&15, row=(lane>>4)*4+reg. Plain stores.
    #pragma unroll
    for (int mi = 0; mi < 8; ++mi) {
        #pragma unroll
        for (int ni = 0; ni < 4; ++ni) {
            #pragma unroll
            for (int r = 0; r < 4; ++r) {
                const int orow = bm0 + wr * 128 + mi * 16 + lk * 4 + r;
                const int ocol = bn0 + wc * 64 + ni * 16 + lm;
                C[(size_t)orow * NN + ocol] = (float)(_Float16)acc[mi][ni][r];
            }
        }
    }
}

// ---------------------------------------------------------------------------
// 128x128 m97-structure GEMM (gemm1: M=2048,N=4096 -> 512 blocks at 128^2).
// ---------------------------------------------------------------------------
template<int K, int N, bool OUT_IS_F32>
__global__ __launch_bounds__(256)
void gemm_tt(const _Float16* __restrict__ A, const _Float16* __restrict__ Bt,
             void* __restrict__ Cv)
{
    __shared__ __align__(16) _Float16 As[BM * BK];   // 8 KB [m][k]
    __shared__ __align__(16) _Float16 Bs[BN * BK];   // 8 KB [n][k]

    const int tid  = threadIdx.x;
    const int lane = tid & 63;
    const int wave = tid >> 6;

    const int bm0 = blockIdx.x * BM;
    const int bn0 = blockIdx.y * BN;

    const int m_off = (wave >> 1) * 64;
    const int n_off = (wave & 1) * 64;

    const int lm = lane & 15;
    const int lk = lane >> 4;

    f32x4 acc[4][4];
    #pragma unroll
    for (int i = 0; i < 4; ++i)
        #pragma unroll
        for (int j = 0; j < 4; ++j)
            acc[i][j] = (f32x4)0.0f;

    for (int kt = 0; kt < K / BK; ++kt) {
        const int k0 = kt * BK;

        #pragma unroll
        for (int issue = 0; issue < 2; ++issue) {
            const int c = issue * 256 + tid;
            const int r = c >> 2;
            const int cc = (c & 3) * 8;
            __builtin_amdgcn_global_load_lds(
                (const __attribute__((address_space(1))) uint32_t*)
                    (A + (size_t)(bm0 + r) * K + k0 + cc),
                (__attribute__((address_space(3))) uint32_t*)&As[c * 8],
                16, 0, 0);
            __builtin_amdgcn_global_load_lds(
                (const __attribute__((address_space(1))) uint32_t*)
                    (Bt + (size_t)(bn0 + r) * K + k0 + cc),
                (__attribute__((address_space(3))) uint32_t*)&Bs[c * 8],
                16, 0, 0);
        }

        __syncthreads();

        half8 af[4], bfr[4];
        #pragma unroll
        for (int mi = 0; mi < 4; ++mi)
            af[mi] = *(const half8*)&As[(m_off + mi * 16 + lm) * BK + lk * 8];
        #pragma unroll
        for (int ni = 0; ni < 4; ++ni)
            bfr[ni] = *(const half8*)&Bs[(n_off + ni * 16 + lm) * BK + lk * 8];

        #pragma unroll
        for (int mi = 0; mi < 4; ++mi)
            #pragma unroll
            for (int ni = 0; ni < 4; ++ni)
                acc[mi][ni] = __builtin_amdgcn_mfma_f32_16x16x32_f16(
                    af[mi], bfr[ni], acc[mi][ni], 0, 0, 0);

        __syncthreads();
    }

    #pragma unroll
    for (int mi = 0; mi < 4; ++mi) {
        #pragma unroll
        for (int ni = 0; ni < 4; ++ni) {
            #pragma unroll
            for (int r = 0; r < 4; ++r) {
                const int orow = bm0 + m_off + mi * 16 + lk * 4 + r;
                const int ocol = bn0 + n_off + ni * 16 + lm;
                const _Float16 h = (_Float16)acc[mi][ni][r];
                if (OUT_IS_F32) ((float*)Cv)[(size_t)orow * N + ocol] = (float)h;
                else            ((_Float16*)Cv)[(size_t)orow * N + ocol] = h;
            }
        }
    }
}

// ---------------------------------------------------------------------------
// Fallback path (passing): NN GEMM with in-kernel transpose staging.
// ---------------------------------------------------------------------------
template<int K, int N, bool A_IS_F16, bool OUT_IS_F32>
__global__ __launch_bounds__(256)
void gemm_nn(const void* __restrict__ Av, const float* __restrict__ B,
             void* __restrict__ Cv)
{
    __shared__ __align__(16) _Float16 As[BM * BK];
    __shared__ __align__(16) _Float16 Bl[BN * BLSTRIDE];

    const int tid  = threadIdx.x;
    const int lane = tid & 63;
    const int wave = tid >> 6;
    const int bm0 = blockIdx.x * BM;
    const int bn0 = blockIdx.y * BN;
    const int m_off = (wave >> 1) * 64;
    const int n_off = (wave & 1) * 64;
    const int lm = lane & 15;
    const int lk = lane >> 4;

    f32x4 acc[4][4];
    #pragma unroll
    for (int i = 0; i < 4; ++i)
        #pragma unroll
        for (int j = 0; j < 4; ++j)
            acc[i][j] = (f32x4)0.0f;

    const int arow = tid >> 2;
    const int acol = (tid & 3) * 8;
    const int bn_local = tid & 127;
    const int kh       = tid >> 7;

    const float*    Af32 = (const float*)Av;
    const _Float16* Af16 = (const _Float16*)Av;
    const float*    Bp   = B + (size_t)(kh * 16) * N + bn0 + bn_local;

    for (int kt = 0; kt < K / BK; ++kt) {
        const int k0 = kt * BK;
        half8 a0, a1;
        if (A_IS_F16) {
            a0 = *(const half8*)(Af16 + (size_t)(bm0 + arow)      * K + k0 + acol);
            a1 = *(const half8*)(Af16 + (size_t)(bm0 + arow + 64) * K + k0 + acol);
        } else {
            const float* r0 = Af32 + (size_t)(bm0 + arow)      * K + k0 + acol;
            const float* r1 = Af32 + (size_t)(bm0 + arow + 64) * K + k0 + acol;
            float4 x0 = *(const float4*)r0, x1 = *(const float4*)(r0 + 4);
            float4 y0 = *(const float4*)r1, y1 = *(const float4*)(r1 + 4);
            a0[0]=(_Float16)x0.x; a0[1]=(_Float16)x0.y; a0[2]=(_Float16)x0.z; a0[3]=(_Float16)x0.w;
            a0[4]=(_Float16)x1.x; a0[5]=(_Float16)x1.y; a0[6]=(_Float16)x1.z; a0[7]=(_Float16)x1.w;
            a1[0]=(_Float16)y0.x; a1[1]=(_Float16)y0.y; a1[2]=(_Float16)y0.z; a1[3]=(_Float16)y0.w;
            a1[4]=(_Float16)y1.x; a1[5]=(_Float16)y1.y; a1[6]=(_Float16)y1.z; a1[7]=(_Float16)y1.w;
        }
        const float* p = Bp + (size_t)k0 * N;
        half8 w0, w1;
        #pragma unroll
        for (int i = 0; i < 8; ++i) w0[i] = (_Float16)p[(size_t)i * N];
        #pragma unroll
        for (int i = 0; i < 8; ++i) w1[i] = (_Float16)p[(size_t)(8 + i) * N];

        *(half8*)&As[arow * BK + acol]        = a0;
        *(half8*)&As[(arow + 64) * BK + acol] = a1;
        *(half8*)&Bl[bn_local * BLSTRIDE + kh * 16]     = w0;
        *(half8*)&Bl[bn_local * BLSTRIDE + kh * 16 + 8] = w1;

        __syncthreads();

        half8 af[4], bfr[4];
        #pragma unroll
        for (int mi = 0; mi < 4; ++mi)
            af[mi] = *(const half8*)&As[(m_off + mi * 16 + lm) * BK + lk * 8];
        #pragma unroll
        for (int ni = 0; ni < 4; ++ni)
            bfr[ni] = *(const half8*)&Bl[(n_off + ni * 16 + lm) * BLSTRIDE + lk * 8];

        #pragma unroll
        for (int mi = 0; mi < 4; ++mi)
            #pragma unroll
            for (int ni = 0; ni < 4; ++ni)
                acc[mi][ni] = __builtin_amdgcn_mfma_f32_16x16x32_f16(
                    af[mi], bfr[ni], acc[mi][ni], 0, 0, 0);

        __syncthreads();
    }

    #pragma unroll
    for (int mi = 0; mi < 4; ++mi) {
        #pragma unroll
        for (int ni = 0; ni < 4; ++ni) {
            #pragma unroll
            for (int r = 0; r < 4; ++r) {
                const int orow = bm0 + m_off + mi * 16 + lk * 4 + r;
                const int ocol = bn0 + n_off + ni * 16 + lm;
                const _Float16 h = (_Float16)acc[mi][ni][r];
                if (OUT_IS_F32) ((float*)Cv)[(size_t)orow * N + ocol] = (float)h;
                else            ((_Float16*)Cv)[(size_t)orow * N + ocol] = h;
            }
        }
    }
}

extern "C" void kernel_launch(void* const* d_in, const int* in_sizes, int n_in,
                              void* d_out, int out_size, void* d_ws, size_t ws_size,
                              hipStream_t stream) {
    const float* A  = (const float*)d_in[0];
    const float* Wp = (const float*)d_in[1];
    const float* Wu = (const float*)d_in[2];

    const size_t MB = 1024 * 1024;
    const size_t need = 192 * MB;   // A16(16) + Wpt(32) + Wut(128) + act(16)

    if (ws_size >= need) {
        _Float16* A16 = (_Float16*)((char*)d_ws);
        _Float16* Wpt = (_Float16*)((char*)d_ws + 16 * MB);
        _Float16* Wut = (_Float16*)((char*)d_ws + 48 * MB);
        _Float16* act = (_Float16*)((char*)d_ws + 176 * MB);

        // Prepass: convert A, transpose+convert both weights (tagged kernels).
        cvt_f32_f16<<<(2048 * 4096 / 4 + 255) / 256, 256, 0, stream>>>(A, A16, 2048 * 4096 / 4);
        transpose_cvt<0><<<dim3(4096 / 64, 4096 / 64), 256, 0, stream>>>(Wp, Wpt, 4096, 4096);
        transpose_cvt<1><<<dim3(16384 / 64, 4096 / 64), 256, 0, stream>>>(Wu, Wut, 4096, 16384);

        // act = fp16(A @ W_prev): 128^2 m97 path (512 blocks).
        gemm_tt<4096, 4096, false>
            <<<dim3(2048 / BM, 4096 / BN), 256, 0, stream>>>(A16, Wpt, act);
        // out = fp32(fp16(act @ W_up)): 256^2 8-phase path, B-pinned mapping.
        gemm_tt8<4096, 16384>
            <<<dim3(512), 512, 0, stream>>>(act, Wut, (float*)d_out);
    } else {
        void* act = d_ws;
        gemm_nn<4096, 4096, false, false>
            <<<dim3(2048 / BM, 4096 / BN), 256, 0, stream>>>(A, Wp, act);
        gemm_nn<4096, 16384, true, true>
            <<<dim3(2048 / BM, 16384 / BN), 256, 0, stream>>>(act, Wu, d_out);
    }
}